// Round 11
// baseline (215.934 us; speedup 1.0000x reference)
//
#include <hip/hip_runtime.h>
#include <hip/hip_bf16.h>

#define KDIM 4096
#define NTILE 64                 // K-tiles of 64
#define NELEM16 (1u << 24)       // 4096*4096 elems per matrix

typedef float f32x4 __attribute__((ext_vector_type(4)));
typedef short bf16x8 __attribute__((ext_vector_type(8)));

typedef const __attribute__((address_space(1))) unsigned int g_u32;
typedef __attribute__((address_space(3))) unsigned int l_u32;

__device__ __forceinline__ void gload_lds16(const void* g, void* l) {
    __builtin_amdgcn_global_load_lds((g_u32*)g, (l_u32*)l, 16, 0, 0);
}

__device__ __forceinline__ unsigned int pack_bf16x2(float lo, float hi) {
    __hip_bfloat162 h = __float22bfloat162_rn(float2{lo, hi});
    union { __hip_bfloat162 h; unsigned int u; } c; c.h = h; return c.u;
}

// ---- pack pass (same images as r8, verified) ----
// x -> A-image: [rt16][kt64][rh2][rl128][cp8][8e], content col-chunk = (cp^(rl&7))*8 (XOR-swz)
// W -> B-frag image: [ot16][kt64][f16][s2][lane64][8e]:
//      W[ot*256+f*16+(lane&15)][kt*64+s*32+(lane>>4)*8+e]  (fragment-contiguous)
__global__ __launch_bounds__(256)
void pack2(const float* __restrict__ x, const float* __restrict__ W,
           unsigned short* __restrict__ xb, unsigned short* __restrict__ wb)
{
    const unsigned int stride = gridDim.x * blockDim.x;
    for (unsigned int i = blockIdx.x * blockDim.x + threadIdx.x; i < (1u << 22); i += stride) {
        const float* __restrict__ in;
        unsigned short* __restrict__ out;
        unsigned int row, col, E;
        if (i < (1u << 21)) {                    // A-image (x)
            const unsigned int cp = i & 7;
            const unsigned int rl = (i >> 3) & 127;
            const unsigned int c  = cp ^ (rl & 7);
            const unsigned int h  = (i >> 10) & 1;
            const unsigned int kt = (i >> 11) & 63;
            const unsigned int rt = i >> 17;
            row = rt * 256 + h * 128 + rl;
            col = kt * 64 + c * 8;
            in = x; out = xb; E = i * 8;
        } else {                                 // B-frag image (W)
            const unsigned int j    = i - (1u << 21);
            const unsigned int lane = j & 63;
            const unsigned int s    = (j >> 6) & 1;
            const unsigned int cf   = (j >> 7) & 15;
            const unsigned int kt   = (j >> 11) & 63;
            const unsigned int ot   = j >> 17;
            row = ot * 256 + cf * 16 + (lane & 15);
            col = kt * 64 + s * 32 + (lane >> 4) * 8;
            in = W; out = wb; E = j * 8;
        }
        const float4* sp = (const float4*)(in + (size_t)row * KDIM + col);
        const float4 a = sp[0], b = sp[1];
        uint4 o;
        o.x = pack_bf16x2(a.x, a.y); o.y = pack_bf16x2(a.z, a.w);
        o.z = pack_bf16x2(b.x, b.y); o.w = pack_bf16x2(b.z, b.w);
        *(uint4*)(out + (size_t)E) = o;
    }
}

// ---- 256x256 GEMM, phase = (tile, K-half), 8-region LDS ring, one-phase-ahead ----
// LDS: 8 regions x 8192 elems (16 KB); region r holds A rowhalf-block (tile,rh)
// with blockIndex = tile*2+rh, r = blockIndex & 7.  Stage-ahead = 4 blocks.
#define STAGE_A(kt, rh, rg)                                                     \
    {                                                                           \
        const unsigned short* g_ = Abase + ((size_t)(kt) * 2 + (rh)) * 8192;    \
        const unsigned int lo_ = (rg) * 8192 + wid * 1024;                      \
        gload_lds16(g_ + stageOff,       &lds[lo_]);                            \
        gload_lds16(g_ + stageOff + 512, &lds[lo_ + 512]);                      \
    }

// read 8 A-frags (rows: mf 0..3 from region R0 = rowhalf0, mf 4..7 from R1) at k-half KH
#define READ_A8(dst, R0, R1, KH)                                                \
    _Pragma("unroll") for (int m = 0; m < 4; ++m)                               \
        dst[m]     = *(const bf16x8*)&lds[(R0) * 8192 + (m * 2 + wm) * 1024 + rdBase + kcp[KH]]; \
    _Pragma("unroll") for (int m = 0; m < 4; ++m)                               \
        dst[4 + m] = *(const bf16x8*)&lds[(R1) * 8192 + (m * 2 + wm) * 1024 + rdBase + kcp[KH]];

// 4 B-frags (cols (n*4+wn)*16) at (tile kt, k-half KH): coalesced dwordx4 each
#define LOAD_B4(dst, kt, KH)                                                    \
    _Pragma("unroll") for (int n = 0; n < 4; ++n)                               \
        dst[n] = *(const bf16x8*)&Bb[(size_t)(kt) * 16384 +                     \
            (((n * 4 + wn) * 2 + (KH)) * 512) + lane * 8];

#define MFMA32(AB, BB)                                                          \
    __builtin_amdgcn_s_setprio(1);                                              \
    _Pragma("unroll") for (int mf = 0; mf < 8; ++mf)                            \
      _Pragma("unroll") for (int nf = 0; nf < 4; ++nf)                          \
        acc[mf][nf] = __builtin_amdgcn_mfma_f32_16x16x32_bf16(                  \
            AB[mf], BB[nf], acc[mf][nf], 0, 0, 0);                              \
    __builtin_amdgcn_s_setprio(0);

// Full phase: stage block (stage-ahead 4) -> vmcnt(18) -> BAR -> issue next-phase
// reads/loads -> MFMA current banks.  vmcnt(18) = 3 phases x (2 stage + 4 B) newer
// ops -> drains exactly the stage whose region is read THIS phase (RAW).  WAR: each
// region's last reader is >= 2 barriers before its re-stage (ring arithmetic).
#define PH_F(STT, STRH, STRG, RDT, RDKH, RR0, RR1, AR, BR, AM, BM)              \
    {                                                                           \
        STAGE_A(STT, STRH, STRG);                                               \
        asm volatile("s_waitcnt vmcnt(18)" ::: "memory");                       \
        __builtin_amdgcn_s_barrier();                                           \
        __builtin_amdgcn_sched_barrier(0);                                      \
        READ_A8(AR, RR0, RR1, RDKH);                                            \
        LOAD_B4(BR, RDT, RDKH);                                                 \
        __builtin_amdgcn_sched_barrier(0);                                      \
        MFMA32(AM, BM);                                                         \
    }

#define PH_N(RDT, RDKH, RR0, RR1, AR, BR, AM, BM)                               \
    {                                                                           \
        asm volatile("s_waitcnt vmcnt(0)" ::: "memory");                        \
        __builtin_amdgcn_s_barrier();                                           \
        __builtin_amdgcn_sched_barrier(0);                                      \
        READ_A8(AR, RR0, RR1, RDKH);                                            \
        LOAD_B4(BR, RDT, RDKH);                                                 \
        __builtin_amdgcn_sched_barrier(0);                                      \
        MFMA32(AM, BM);                                                         \
    }

#define PH_L(AM, BM)                                                            \
    {                                                                           \
        asm volatile("s_waitcnt vmcnt(0)" ::: "memory");                        \
        __builtin_amdgcn_s_barrier();                                           \
        __builtin_amdgcn_sched_barrier(0);                                      \
        MFMA32(AM, BM);                                                         \
    }

// group of 4 tiles (8 phases); regions cycle 0..7 (TB multiple of 4)
#define GROUP(TB)                                                               \
    PH_F((TB)+2, 0, 4, (TB),   1, 0, 1, aO, bO, aE, bE)                         \
    PH_F((TB)+2, 1, 5, (TB)+1, 0, 2, 3, aE, bE, aO, bO)                         \
    PH_F((TB)+3, 0, 6, (TB)+1, 1, 2, 3, aO, bO, aE, bE)                         \
    PH_F((TB)+3, 1, 7, (TB)+2, 0, 4, 5, aE, bE, aO, bO)                         \
    PH_F((TB)+4, 0, 0, (TB)+2, 1, 4, 5, aO, bO, aE, bE)                         \
    PH_F((TB)+4, 1, 1, (TB)+3, 0, 6, 7, aE, bE, aO, bO)                         \
    PH_F((TB)+5, 0, 2, (TB)+3, 1, 6, 7, aO, bO, aE, bE)                         \
    PH_F((TB)+5, 1, 3, (TB)+4, 0, 0, 1, aE, bE, aO, bO)

__global__ __launch_bounds__(512, 1)
void gemm_ring(const unsigned short* __restrict__ A,
               const unsigned short* __restrict__ B,
               const float* __restrict__ bias,
               float* __restrict__ out)
{
    __shared__ unsigned short lds[65536];   // 128 KiB: 8 regions x 16 KB

    const int tid  = threadIdx.x;
    const int lane = tid & 63;
    const int wid  = tid >> 6;     // 0..7
    const int wm   = wid >> 2;     // 0..1
    const int wn   = wid & 3;      // 0..3
    const int c15  = lane & 15;
    const int q4   = lane >> 4;
    const int c7   = c15 & 7;

    // 256 blocks = 16x16 output tiles; XCD-bijective swizzle (256 % 8 == 0)
    const int bid = blockIdx.x;
    const int wg  = (bid & 7) * 32 + (bid >> 3);
    const int bm  = wg >> 4;
    const int bn  = wg & 15;

    const unsigned short* Abase = A + ((size_t)bm << 20);
    const unsigned short* Bb    = B + ((size_t)bn << 20);

    const int stageOff = wid * 1024 + lane * 8;   // within a 16 KB block
    const int rdBase   = c15 * 64;
    const int kcp[2]   = { ((0 + q4) ^ c7) * 8, ((4 + q4) ^ c7) * 8 };

    f32x4 acc[8][4];
    #pragma unroll
    for (int i = 0; i < 8; ++i)
        #pragma unroll
        for (int j = 0; j < 4; ++j)
            acc[i][j] = (f32x4)0.0f;

    bf16x8 aE[8], aO[8];    // A banks (even/odd phase), 32 VGPR each
    bf16x8 bE[4], bO[4];    // B banks, 16 VGPR each

    // prologue: stage blocks 0..3 (tiles 0,1 both rowhalves) -> regions 0..3
    STAGE_A(0, 0, 0);
    STAGE_A(0, 1, 1);
    STAGE_A(1, 0, 2);
    STAGE_A(1, 1, 3);
    asm volatile("s_waitcnt vmcnt(0)" ::: "memory");
    __builtin_amdgcn_s_barrier();
    __builtin_amdgcn_sched_barrier(0);
    READ_A8(aE, 0, 1, 0);    // tile0, k-half0
    LOAD_B4(bE, 0, 0);

    for (int TB = 0; TB < 60; TB += 4) {
        GROUP(TB)
    }
    // tail group TB=60 (stages end at block 127; reads end at phase 127)
    PH_F(62, 0, 4, 60, 1, 0, 1, aO, bO, aE, bE)
    PH_F(62, 1, 5, 61, 0, 2, 3, aE, bE, aO, bO)
    PH_F(63, 0, 6, 61, 1, 2, 3, aO, bO, aE, bE)
    PH_F(63, 1, 7, 62, 0, 4, 5, aE, bE, aO, bO)
    PH_N(62, 1, 4, 5, aO, bO, aE, bE)
    PH_N(63, 0, 6, 7, aE, bE, aO, bO)
    PH_N(63, 1, 6, 7, aO, bO, aE, bE)
    PH_L(aO, bO)

    // Epilogue: bias + maxpool(4 along col) + sum + atomic row add.
    // C/D frag: col = c15, row = q4*4 + r. Wave cols: (nf*4+wn)*16 + c15.
    float rs[8][4];
    #pragma unroll
    for (int mf = 0; mf < 8; ++mf)
        #pragma unroll
        for (int r = 0; r < 4; ++r)
            rs[mf][r] = 0.0f;

    #pragma unroll
    for (int nf = 0; nf < 4; ++nf) {
        const float bv = bias[bn * 256 + (nf * 4 + wn) * 16 + c15];
        #pragma unroll
        for (int mf = 0; mf < 8; ++mf) {
            #pragma unroll
            for (int r = 0; r < 4; ++r) {
                float v = acc[mf][nf][r] + bv;
                v = fmaxf(v, __shfl_xor(v, 1));
                v = fmaxf(v, __shfl_xor(v, 2));
                v += __shfl_xor(v, 4);
                v += __shfl_xor(v, 8);
                rs[mf][r] += v;
            }
        }
    }

    if (c15 == 0) {
        #pragma unroll
        for (int mf = 0; mf < 8; ++mf)
            #pragma unroll
            for (int r = 0; r < 4; ++r) {
                const int row = bm * 256 + (mf * 2 + wm) * 16 + q4 * 4 + r;
                atomicAdd(&out[row], 0.5f * rs[mf][r]);
            }
    }
}

// ---------------- fallback (round-1 kernel, verified) if d_ws too small ----------------
__global__ __launch_bounds__(256, 2)
void fused_gemm_pool_fallback(const float* __restrict__ x,
                              const float* __restrict__ W,
                              const float* __restrict__ b,
                              float* __restrict__ out)
{
    __shared__ unsigned short As[128][72];
    __shared__ unsigned short Bs[128][72];

    const int tid  = threadIdx.x;
    const int lane = tid & 63;
    const int wid  = tid >> 6;
    const int wm   = wid >> 1;
    const int wn   = wid & 1;

    const int bid = blockIdx.x;
    const int wg  = (bid & 7) * 128 + (bid >> 3);
    const int bm  = wg >> 5;
    const int bn  = wg & 31;

    const int srow = tid >> 4;
    const int scol = tid & 15;

    const float* xbase = x + (size_t)(bm * 128 + srow) * KDIM + scol * 4;
    const float* wbase = W + (size_t)(bn * 128 + srow) * KDIM + scol * 4;

    f32x4 acc[4][4];
    #pragma unroll
    for (int i = 0; i < 4; ++i)
        #pragma unroll
        for (int j = 0; j < 4; ++j)
            acc[i][j] = (f32x4)0.0f;

    float4 ra[8], rb[8];
    #pragma unroll
    for (int p = 0; p < 8; ++p) {
        ra[p] = *(const float4*)(xbase + (size_t)(p * 16) * KDIM);
        rb[p] = *(const float4*)(wbase + (size_t)(p * 16) * KDIM);
    }

    for (int kt = 0; kt < KDIM / 64; ++kt) {
        #pragma unroll
        for (int p = 0; p < 8; ++p) {
            const int r = srow + p * 16;
            uint2 pa, pb;
            pa.x = pack_bf16x2(ra[p].x, ra[p].y);
            pa.y = pack_bf16x2(ra[p].z, ra[p].w);
            pb.x = pack_bf16x2(rb[p].x, rb[p].y);
            pb.y = pack_bf16x2(rb[p].z, rb[p].w);
            *(uint2*)&As[r][scol * 4] = pa;
            *(uint2*)&Bs[r][scol * 4] = pb;
        }
        __syncthreads();

        if (kt + 1 < KDIM / 64) {
            const float* xa = xbase + (size_t)(kt + 1) * 64;
            const float* wa = wbase + (size_t)(kt + 1) * 64;
            #pragma unroll
            for (int p = 0; p < 8; ++p) {
                ra[p] = *(const float4*)(xa + (size_t)(p * 16) * KDIM);
                rb[p] = *(const float4*)(wa + (size_t)(p * 16) * KDIM);
            }
        }

        #pragma unroll
        for (int k0 = 0; k0 < 2; ++k0) {
            const int kk = k0 * 32 + (lane >> 4) * 8;
            bf16x8 af[4], bfr[4];
            #pragma unroll
            for (int mf = 0; mf < 4; ++mf)
                af[mf] = *(const bf16x8*)&As[wm * 64 + mf * 16 + (lane & 15)][kk];
            #pragma unroll
            for (int nf = 0; nf < 4; ++nf)
                bfr[nf] = *(const bf16x8*)&Bs[wn * 64 + nf * 16 + (lane & 15)][kk];
            #pragma unroll
            for (int mf = 0; mf < 4; ++mf)
                #pragma unroll
                for (int nf = 0; nf < 4; ++nf)
                    acc[mf][nf] = __builtin_amdgcn_mfma_f32_16x16x32_bf16(
                        af[mf], bfr[nf], acc[mf][nf], 0, 0, 0);
        }
        __syncthreads();
    }

    float rs[4][4];
    #pragma unroll
    for (int mf = 0; mf < 4; ++mf)
        #pragma unroll
        for (int r = 0; r < 4; ++r)
            rs[mf][r] = 0.0f;

    #pragma unroll
    for (int nf = 0; nf < 4; ++nf) {
        const float bv = b[bn * 128 + wn * 64 + nf * 16 + (lane & 15)];
        #pragma unroll
        for (int mf = 0; mf < 4; ++mf) {
            #pragma unroll
            for (int r = 0; r < 4; ++r) {
                float v = acc[mf][nf][r] + bv;
                v = fmaxf(v, __shfl_xor(v, 1));
                v = fmaxf(v, __shfl_xor(v, 2));
                v += __shfl_xor(v, 4);
                v += __shfl_xor(v, 8);
                rs[mf][r] += v;
            }
        }
    }

    if ((lane & 15) == 0) {
        #pragma unroll
        for (int mf = 0; mf < 4; ++mf)
            #pragma unroll
            for (int r = 0; r < 4; ++r) {
                const int row = bm * 128 + wm * 64 + mf * 16 + (lane >> 4) * 4 + r;
                atomicAdd(&out[row], 0.5f * rs[mf][r]);
            }
    }
}

extern "C" void kernel_launch(void* const* d_in, const int* in_sizes, int n_in,
                              void* d_out, int out_size, void* d_ws, size_t ws_size,
                              hipStream_t stream) {
    const float* x = (const float*)d_in[0];
    const float* W = (const float*)d_in[1];
    const float* b = (const float*)d_in[2];
    float* out = (float*)d_out;

    hipMemsetAsync(out, 0, (size_t)out_size * sizeof(float), stream);

    const size_t need = (size_t)NELEM16 * 2 * sizeof(unsigned short); // 64 MB
    if (ws_size >= need) {
        unsigned short* xb = (unsigned short*)d_ws;
        unsigned short* wb = xb + (size_t)NELEM16;
        pack2<<<dim3(2048), dim3(256), 0, stream>>>(x, W, xb, wb);
        gemm_ring<<<dim3(256), dim3(512), 0, stream>>>(xb, wb, b, out);
    } else {
        fused_gemm_pool_fallback<<<dim3(1024), dim3(256), 0, stream>>>(x, W, b, out);
    }
}

// Round 12
// 167.787 us; speedup vs baseline: 1.2870x; 1.2870x over previous
//
#include <hip/hip_runtime.h>
#include <hip/hip_bf16.h>

#define KDIM 4096
#define NTILE 64                 // K-tiles of 64
#define NELEM16 (1u << 24)       // 4096*4096 elems per matrix

typedef float f32x4 __attribute__((ext_vector_type(4)));
typedef short bf16x8 __attribute__((ext_vector_type(8)));

typedef const __attribute__((address_space(1))) unsigned int g_u32;
typedef __attribute__((address_space(3))) unsigned int l_u32;

__device__ __forceinline__ void gload_lds16(const void* g, void* l) {
    __builtin_amdgcn_global_load_lds((g_u32*)g, (l_u32*)l, 16, 0, 0);
}

__device__ __forceinline__ unsigned int pack_bf16x2(float lo, float hi) {
    __hip_bfloat162 h = __float22bfloat162_rn(float2{lo, hi});
    union { __hip_bfloat162 h; unsigned int u; } c; c.h = h; return c.u;
}

// ---- pack fp32 -> tiled + XOR-swizzled bf16 staging images (both matrices) ----
// layout: [rt16][kt64][half2] 16KB blocks; within: rl(128) x cp(8) x 8e,
// content of (rl,cp) = source row rt*256+h*128+rl, cols kt*64 + (cp^(rl&7))*8
__global__ __launch_bounds__(256)
void pack_swz2(const float* __restrict__ x, const float* __restrict__ W,
               unsigned short* __restrict__ xb, unsigned short* __restrict__ wb)
{
    const unsigned int stride = gridDim.x * blockDim.x;
    for (unsigned int i = blockIdx.x * blockDim.x + threadIdx.x; i < (1u << 22); i += stride) {
        const unsigned int j  = i & ((1u << 21) - 1);
        const float* __restrict__ in = (i >> 21) ? W : x;
        unsigned short* __restrict__ out = (i >> 21) ? wb : xb;
        const unsigned int cp = j & 7;
        const unsigned int rl = (j >> 3) & 127;
        const unsigned int c  = cp ^ (rl & 7);
        const unsigned int h  = (j >> 10) & 1;
        const unsigned int kt = (j >> 11) & 63;
        const unsigned int rt = j >> 17;
        const unsigned int row = rt * 256 + h * 128 + rl;
        const unsigned int col = kt * 64 + c * 8;
        const float4* s = (const float4*)(in + (size_t)row * KDIM + col);
        const float4 a = s[0], b = s[1];
        uint4 o;
        o.x = pack_bf16x2(a.x, a.y); o.y = pack_bf16x2(a.z, a.w);
        o.z = pack_bf16x2(b.x, b.y); o.w = pack_bf16x2(b.z, b.w);
        *(uint4*)(out + (size_t)j * 8) = o;
    }
}

// ---- 256x256 GEMM, faithful m201 8-phase template, fused pool epilogue ----
// LDS elem offsets: buf*32768 + op*16384 + half*8192 + rowfrag*1024 + c15*64 + swz*8
#define STAGE(matBase, kt, h, bufn, opIdx)                                      \
    {                                                                           \
        const unsigned short* g_ = (matBase) + ((size_t)(kt) * 2 + (h)) * 8192; \
        const unsigned int lo_ = (bufn) * 32768 + (opIdx) * 16384 + (h) * 8192 + wid * 1024; \
        gload_lds16(g_ + stageOff,       &lds[lo_]);                            \
        gload_lds16(g_ + stageOff + 512, &lds[lo_ + 512]);                      \
    }

#define READ_A(dst, base)                                                       \
    _Pragma("unroll") for (int m = 0; m < 4; ++m)                               \
      _Pragma("unroll") for (int k = 0; k < 2; ++k)                             \
        dst[m][k] = *(const bf16x8*)&lds[(base) + (m * 2 + wm) * 1024 + rdBase + kcp[k]];

#define READ_B(dst, base)                                                       \
    _Pragma("unroll") for (int n = 0; n < 2; ++n)                               \
      _Pragma("unroll") for (int k = 0; k < 2; ++k)                             \
        dst[n][k] = *(const bf16x8*)&lds[(base) + (n * 4 + wn) * 1024 + rdBase + kcp[k]];

// One phase: {reads; stage ONE half; BAR; setprio; 16 MFMA; setprio; [vmcnt]; BAR}
// Compiler inserts counted lgkmcnt between ds_reads and dependent MFMAs (m97).
#define PHASE(RDS, STG, AF, BF, MO, NO, VMW)                                    \
    {                                                                           \
        RDS;                                                                    \
        STG;                                                                    \
        __builtin_amdgcn_s_barrier();                                           \
        __builtin_amdgcn_s_setprio(1);                                          \
        _Pragma("unroll") for (int m = 0; m < 4; ++m)                           \
          _Pragma("unroll") for (int n = 0; n < 2; ++n)                         \
            _Pragma("unroll") for (int k = 0; k < 2; ++k)                       \
              acc[(MO) + m][(NO) + n] = __builtin_amdgcn_mfma_f32_16x16x32_bf16(\
                  AF[m][k], BF[n][k], acc[(MO) + m][(NO) + n], 0, 0, 0);        \
        __builtin_amdgcn_s_setprio(0);                                          \
        VMW;                                                                    \
        __builtin_amdgcn_s_barrier();                                           \
    }

#define VM6 asm volatile("s_waitcnt vmcnt(6)" ::: "memory")
#define VM0 asm volatile("s_waitcnt vmcnt(0)" ::: "memory")

// Iteration over tiles (t, t+1), t even: tile t in buf0, t+1 in buf1.
// Quads per tile: P1:(A0,B0) P2:(A0,B1) P3:(A1,B1) P4:(A1,B0); reads {12,4,8,0}.
// Stage ring (1 half/phase, ring verified WAR>=1 barrier / RAW via vmcnt+barrier):
//   P1:A1(t+1)->b1f  P2:A0(t+2)->b0  P3:B0(t+2)->b0  P4:B1(t+2)->b0
//   P5:A1(t+2)->b0   P6:A0(t+3)->b1f P7:B0(t+3)->b1f P8:B1(t+3)->b1f
// vmcnt(6) at P4/P8 only -> exactly 3 half-tiles stay in flight.
#define ITER(t)                                                                 \
    PHASE(READ_A(afr, 0); READ_B(b0, 16384),                                    \
          STAGE(Abase, (t)+1, 1, 1, 0), afr, b0, 0, 0, )                        \
    PHASE(READ_B(b1, 16384 + 8192),                                             \
          STAGE(Abase, (t)+2, 0, 0, 0), afr, b1, 0, 2, )                        \
    PHASE(READ_A(afr, 8192),                                                    \
          STAGE(Bbase, (t)+2, 0, 0, 1), afr, b1, 4, 2, )                        \
    PHASE(,                                                                     \
          STAGE(Bbase, (t)+2, 1, 0, 1), afr, b0, 4, 0, VM6)                     \
    PHASE(READ_A(afr, 32768); READ_B(b0, 32768 + 16384),                        \
          STAGE(Abase, (t)+2, 1, 0, 0), afr, b0, 0, 0, )                        \
    PHASE(READ_B(b1, 32768 + 16384 + 8192),                                     \
          STAGE(Abase, (t)+3, 0, 1, 0), afr, b1, 0, 2, )                        \
    PHASE(READ_A(afr, 32768 + 8192),                                            \
          STAGE(Bbase, (t)+3, 0, 1, 1), afr, b1, 4, 2, )                        \
    PHASE(,                                                                     \
          STAGE(Bbase, (t)+3, 1, 1, 1), afr, b0, 4, 0, VM6)

// Last iteration (t = 62): only A1(63) still needs staging (at P1);
// vmcnt(0) at P4 guarantees it (and the prior 3 halves) have landed.
#define ITER_LAST()                                                             \
    PHASE(READ_A(afr, 0); READ_B(b0, 16384),                                    \
          STAGE(Abase, 63, 1, 1, 0), afr, b0, 0, 0, )                           \
    PHASE(READ_B(b1, 16384 + 8192), , afr, b1, 0, 2, )                          \
    PHASE(READ_A(afr, 8192), , afr, b1, 4, 2, )                                 \
    PHASE(, , afr, b0, 4, 0, VM0)                                               \
    PHASE(READ_A(afr, 32768); READ_B(b0, 32768 + 16384), , afr, b0, 0, 0, )     \
    PHASE(READ_B(b1, 32768 + 16384 + 8192), , afr, b1, 0, 2, )                  \
    PHASE(READ_A(afr, 32768 + 8192), , afr, b1, 4, 2, )                         \
    PHASE(, , afr, b0, 4, 0, )

__global__ __launch_bounds__(512, 1)
void gemm_8phase(const unsigned short* __restrict__ A,
                 const unsigned short* __restrict__ B,
                 const float* __restrict__ bias,
                 float* __restrict__ out)
{
    __shared__ unsigned short lds[65536];   // 128 KiB: [buf2][op2][half2][8192]

    const int tid  = threadIdx.x;
    const int lane = tid & 63;
    const int wid  = tid >> 6;     // 0..7
    const int wm   = wid >> 2;     // 0..1
    const int wn   = wid & 3;      // 0..3
    const int c15  = lane & 15;
    const int q4   = lane >> 4;
    const int c7   = c15 & 7;

    // 256 blocks = 16x16 output tiles; XCD-bijective swizzle (256 % 8 == 0)
    const int bid = blockIdx.x;
    const int wg  = (bid & 7) * 32 + (bid >> 3);
    const int bm  = wg >> 4;
    const int bn  = wg & 15;

    const unsigned short* Abase = A + ((size_t)bm << 20);
    const unsigned short* Bbase = B + ((size_t)bn << 20);

    const int stageOff = wid * 1024 + lane * 8;   // elem offset within a 16KB half
    const int rdBase   = c15 * 64;
    const int kcp[2]   = { ((0 + q4) ^ c7) * 8, ((4 + q4) ^ c7) * 8 };

    f32x4 acc[8][4];
    #pragma unroll
    for (int i = 0; i < 8; ++i)
        #pragma unroll
        for (int j = 0; j < 4; ++j)
            acc[i][j] = (f32x4)0.0f;

    bf16x8 afr[4][2];    // A fragments (A0 in P1-P2, A1 in P3-P4)
    bf16x8 b0[2][2];     // B-half0 (live whole tile)
    bf16x8 b1[2][2];     // B-half1 (live P2-P3)

    // prologue: 7 halves, oldest-first so vmcnt(6) drains tile0 entirely
    STAGE(Abase, 0, 0, 0, 0);   // A0(0)
    STAGE(Bbase, 0, 0, 0, 1);   // B0(0)
    STAGE(Bbase, 0, 1, 0, 1);   // B1(0)
    STAGE(Abase, 0, 1, 0, 0);   // A1(0)
    STAGE(Abase, 1, 0, 1, 0);   // A0(1)
    STAGE(Bbase, 1, 0, 1, 1);   // B0(1)
    STAGE(Bbase, 1, 1, 1, 1);   // B1(1)
    VM6;                        // drains tile0's 4 halves; {A0,B0,B1}(1) in flight
    __builtin_amdgcn_s_barrier();

    for (int t = 0; t < 62; t += 2) {
        ITER(t)
    }
    ITER_LAST()

    // Epilogue: bias + maxpool(4 along col) + sum + atomic row add.
    // C/D frag: col = c15, row = q4*4 + r. Wave cols: (nf*4+wn)*16 + c15.
    float rs[8][4];
    #pragma unroll
    for (int mf = 0; mf < 8; ++mf)
        #pragma unroll
        for (int r = 0; r < 4; ++r)
            rs[mf][r] = 0.0f;

    #pragma unroll
    for (int nf = 0; nf < 4; ++nf) {
        const float bv = bias[bn * 256 + (nf * 4 + wn) * 16 + c15];
        #pragma unroll
        for (int mf = 0; mf < 8; ++mf) {
            #pragma unroll
            for (int r = 0; r < 4; ++r) {
                float v = acc[mf][nf][r] + bv;
                v = fmaxf(v, __shfl_xor(v, 1));
                v = fmaxf(v, __shfl_xor(v, 2));
                v += __shfl_xor(v, 4);
                v += __shfl_xor(v, 8);
                rs[mf][r] += v;
            }
        }
    }

    if (c15 == 0) {
        #pragma unroll
        for (int mf = 0; mf < 8; ++mf)
            #pragma unroll
            for (int r = 0; r < 4; ++r) {
                const int row = bm * 256 + (mf * 2 + wm) * 16 + q4 * 4 + r;
                atomicAdd(&out[row], 0.5f * rs[mf][r]);
            }
    }
}

// ---------------- fallback (round-1 kernel, verified) if d_ws too small ----------------
__global__ __launch_bounds__(256, 2)
void fused_gemm_pool_fallback(const float* __restrict__ x,
                              const float* __restrict__ W,
                              const float* __restrict__ b,
                              float* __restrict__ out)
{
    __shared__ unsigned short As[128][72];
    __shared__ unsigned short Bs[128][72];

    const int tid  = threadIdx.x;
    const int lane = tid & 63;
    const int wid  = tid >> 6;
    const int wm   = wid >> 1;
    const int wn   = wid & 1;

    const int bid = blockIdx.x;
    const int wg  = (bid & 7) * 128 + (bid >> 3);
    const int bm  = wg >> 5;
    const int bn  = wg & 31;

    const int srow = tid >> 4;
    const int scol = tid & 15;

    const float* xbase = x + (size_t)(bm * 128 + srow) * KDIM + scol * 4;
    const float* wbase = W + (size_t)(bn * 128 + srow) * KDIM + scol * 4;

    f32x4 acc[4][4];
    #pragma unroll
    for (int i = 0; i < 4; ++i)
        #pragma unroll
        for (int j = 0; j < 4; ++j)
            acc[i][j] = (f32x4)0.0f;

    float4 ra[8], rb[8];
    #pragma unroll
    for (int p = 0; p < 8; ++p) {
        ra[p] = *(const float4*)(xbase + (size_t)(p * 16) * KDIM);
        rb[p] = *(const float4*)(wbase + (size_t)(p * 16) * KDIM);
    }

    for (int kt = 0; kt < KDIM / 64; ++kt) {
        #pragma unroll
        for (int p = 0; p < 8; ++p) {
            const int r = srow + p * 16;
            uint2 pa, pb;
            pa.x = pack_bf16x2(ra[p].x, ra[p].y);
            pa.y = pack_bf16x2(ra[p].z, ra[p].w);
            pb.x = pack_bf16x2(rb[p].x, rb[p].y);
            pb.y = pack_bf16x2(rb[p].z, rb[p].w);
            *(uint2*)&As[r][scol * 4] = pa;
            *(uint2*)&Bs[r][scol * 4] = pb;
        }
        __syncthreads();

        if (kt + 1 < KDIM / 64) {
            const float* xa = xbase + (size_t)(kt + 1) * 64;
            const float* wa = wbase + (size_t)(kt + 1) * 64;
            #pragma unroll
            for (int p = 0; p < 8; ++p) {
                ra[p] = *(const float4*)(xa + (size_t)(p * 16) * KDIM);
                rb[p] = *(const float4*)(wa + (size_t)(p * 16) * KDIM);
            }
        }

        #pragma unroll
        for (int k0 = 0; k0 < 2; ++k0) {
            const int kk = k0 * 32 + (lane >> 4) * 8;
            bf16x8 af[4], bfr[4];
            #pragma unroll
            for (int mf = 0; mf < 4; ++mf)
                af[mf] = *(const bf16x8*)&As[wm * 64 + mf * 16 + (lane & 15)][kk];
            #pragma unroll
            for (int nf = 0; nf < 4; ++nf)
                bfr[nf] = *(const bf16x8*)&Bs[wn * 64 + nf * 16 + (lane & 15)][kk];
            #pragma unroll
            for (int mf = 0; mf < 4; ++mf)
                #pragma unroll
                for (int nf = 0; nf < 4; ++nf)
                    acc[mf][nf] = __builtin_amdgcn_mfma_f32_16x16x32_bf16(
                        af[mf], bfr[nf], acc[mf][nf], 0, 0, 0);
        }
        __syncthreads();
    }

    float rs[4][4];
    #pragma unroll
    for (int mf = 0; mf < 4; ++mf)
        #pragma unroll
        for (int r = 0; r < 4; ++r)
            rs[mf][r] = 0.0f;

    #pragma unroll
    for (int nf = 0; nf < 4; ++nf) {
        const float bv = b[bn * 128 + wn * 64 + nf * 16 + (lane & 15)];
        #pragma unroll
        for (int mf = 0; mf < 4; ++mf) {
            #pragma unroll
            for (int r = 0; r < 4; ++r) {
                float v = acc[mf][nf][r] + bv;
                v = fmaxf(v, __shfl_xor(v, 1));
                v = fmaxf(v, __shfl_xor(v, 2));
                v += __shfl_xor(v, 4);
                v += __shfl_xor(v, 8);
                rs[mf][r] += v;
            }
        }
    }

    if ((lane & 15) == 0) {
        #pragma unroll
        for (int mf = 0; mf < 4; ++mf)
            #pragma unroll
            for (int r = 0; r < 4; ++r) {
                const int row = bm * 128 + wm * 64 + mf * 16 + (lane >> 4) * 4 + r;
                atomicAdd(&out[row], 0.5f * rs[mf][r]);
            }
    }
}

extern "C" void kernel_launch(void* const* d_in, const int* in_sizes, int n_in,
                              void* d_out, int out_size, void* d_ws, size_t ws_size,
                              hipStream_t stream) {
    const float* x = (const float*)d_in[0];
    const float* W = (const float*)d_in[1];
    const float* b = (const float*)d_in[2];
    float* out = (float*)d_out;

    hipMemsetAsync(out, 0, (size_t)out_size * sizeof(float), stream);

    const size_t need = (size_t)NELEM16 * 2 * sizeof(unsigned short); // 64 MB
    if (ws_size >= need) {
        unsigned short* xb = (unsigned short*)d_ws;
        unsigned short* wb = xb + (size_t)NELEM16;
        pack_swz2<<<dim3(2048), dim3(256), 0, stream>>>(x, W, xb, wb);
        gemm_8phase<<<dim3(256), dim3(512), 0, stream>>>(xb, wb, b, out);
    } else {
        fused_gemm_pool_fallback<<<dim3(1024), dim3(256), 0, stream>>>(x, W, b, out);
    }
}